// Round 2
// baseline (595.689 us; speedup 1.0000x reference)
//
#include <hip/hip_runtime.h>
#include <hip/hip_bf16.h>
#include <math.h>

// ---------------------------------------------------------------------------
// GPT block on MI355X (gfx950). bf16 MFMA compute, fp32 accumulate.
// Workspace layout (MB = 1<<20), total 72 MB:
//   [ 0, 6)  WtQKV  bf16 [3072][1024]  (W_Q,W_K,W_V transposed, contiguous)
//   [ 6, 8)  WtO    bf16 [1024][1024]
//   [ 8,16)  Wtfc   bf16 [4096][1024]
//   [16,24)  Wtproj bf16 [1024][4096]
//   [24,32)  zn / ctx   bf16 [4096][1024]
//   [32,40)  Q / h      bf16 [4096][1024]
//   [40,48)  K          bf16 [4096][1024]
//   [48,56)  Vt         bf16 [32][64][2048]  (V transposed per (b,h))
//   [40,72)  ffn1       bf16 [4096][4096]  (overlaps K,Vt — dead after attn)
// d_out doubles as z2 (fp32): O-proj writes z2 = z + attn; proj does +=.
// ---------------------------------------------------------------------------

typedef __bf16 bf16x8 __attribute__((ext_vector_type(8)));
typedef __bf16 bf16x4 __attribute__((ext_vector_type(4)));
typedef float  f32x4  __attribute__((ext_vector_type(4)));

#define MFMA_16x16x32_BF16(A, B, C) __builtin_amdgcn_mfma_f32_16x16x32_bf16((A), (B), (C), 0, 0, 0)

#define GLDS16(g, l) __builtin_amdgcn_global_load_lds( \
    (const __attribute__((address_space(1))) void*)(g), \
    (__attribute__((address_space(3))) void*)(l), 16, 0, 0)

// ---------------- transpose + fp32->bf16 convert:  src[K][N] -> dst[N][K] ----
__global__ __launch_bounds__(256) void transconv_kernel(
    const float* __restrict__ src, __bf16* __restrict__ dst, int K, int N)
{
    __shared__ float tile[32][33];
    const int n0 = blockIdx.x * 32, k0 = blockIdx.y * 32;
    const int c = threadIdx.x & 31, r = threadIdx.x >> 5;
#pragma unroll
    for (int i = 0; i < 4; ++i)
        tile[r + 8 * i][c] = src[(size_t)(k0 + r + 8 * i) * N + n0 + c];
    __syncthreads();
#pragma unroll
    for (int i = 0; i < 4; ++i)
        dst[(size_t)(n0 + r + 8 * i) * K + k0 + c] = (__bf16)tile[c][r + 8 * i];
}

// ---------------- RMSNorm: fp32 [M][1024] -> bf16 [M][1024] -----------------
__global__ __launch_bounds__(256) void rmsnorm_kernel(
    const float* __restrict__ x, const float* __restrict__ gain,
    __bf16* __restrict__ out)
{
    const int row = blockIdx.x, t = threadIdx.x;
    const float4 v = ((const float4*)(x + (size_t)row * 1024))[t];
    float ss = v.x * v.x + v.y * v.y + v.z * v.z + v.w * v.w;
#pragma unroll
    for (int m = 1; m < 64; m <<= 1) ss += __shfl_xor(ss, m);
    __shared__ float red[4];
    const int wid = t >> 6, lane = t & 63;
    if (lane == 0) red[wid] = ss;
    __syncthreads();
    const float tot = red[0] + red[1] + red[2] + red[3];
    const float inv = rsqrtf(tot * (1.0f / 1024.0f) + 1e-5f);
    const float4 gv = ((const float4*)gain)[t];
    __bf16* o = out + (size_t)row * 1024 + t * 4;
    o[0] = (__bf16)(v.x * inv * gv.x);
    o[1] = (__bf16)(v.y * inv * gv.y);
    o[2] = (__bf16)(v.z * inv * gv.z);
    o[3] = (__bf16)(v.w * inv * gv.w);
}

// ---------------- GEMM: C[M][N] = A[M][K] * Bt[N][K]^T, bf16 MFMA ----------
// m97 structure: global_load_lds width 16, linear LDS [tile][64], BK=64.
// EPI: 1 = out_f32 = res + acc; 2 = store bf16 gelu_erf(acc); 3 = out_f32 += acc
// EPI: 4 = fused QKV split: outp = Q base; K at +4M elems; Vt at +8M elems
template <int BM, int BN, int EPI>
__global__ __launch_bounds__(256) void gemm_bf16(
    const __bf16* __restrict__ A, const __bf16* __restrict__ Bt,
    void* __restrict__ outp, const float* __restrict__ res,
    int M, int N, int K)
{
    __shared__ __bf16 As[BM * 64];
    __shared__ __bf16 Bs[BN * 64];
    const int tid = threadIdx.x;
    const int m0 = blockIdx.y * BM, n0 = blockIdx.x * BN;
    const int lane = tid & 63, w = tid >> 6;
    const int wm = w >> 1, wn = w & 1;
    const int lr = lane & 15, g = lane >> 4;
    const int srow = lane >> 3, scol = (lane & 7) * 8;  // staging map

    constexpr int MI = BM / 32, NI = BN / 32;
    f32x4 acc[MI][NI] = {};

    const __bf16* Abase = A + (size_t)m0 * K;
    const __bf16* Bbase = Bt + (size_t)n0 * K;

    for (int kb = 0; kb < K; kb += 64) {
#pragma unroll
        for (int j = 0; j < BM / 32; ++j) {
            const int s = j * 4 + w;
            GLDS16(Abase + (size_t)(s * 8 + srow) * K + kb + scol, &As[s * 512]);
        }
#pragma unroll
        for (int j = 0; j < BN / 32; ++j) {
            const int s = j * 4 + w;
            GLDS16(Bbase + (size_t)(s * 8 + srow) * K + kb + scol, &Bs[s * 512]);
        }
        __syncthreads();

        bf16x8 af[2][MI], bfr[2][NI];
#pragma unroll
        for (int kk = 0; kk < 2; ++kk) {
#pragma unroll
            for (int i = 0; i < MI; ++i)
                af[kk][i] = *(const bf16x8*)&As[(wm * (BM / 2) + i * 16 + lr) * 64 + kk * 32 + g * 8];
#pragma unroll
            for (int i = 0; i < NI; ++i)
                bfr[kk][i] = *(const bf16x8*)&Bs[(wn * (BN / 2) + i * 16 + lr) * 64 + kk * 32 + g * 8];
        }
#pragma unroll
        for (int kk = 0; kk < 2; ++kk)
#pragma unroll
            for (int mi = 0; mi < MI; ++mi)
#pragma unroll
                for (int ni = 0; ni < NI; ++ni)
                    acc[mi][ni] = MFMA_16x16x32_BF16(af[kk][mi], bfr[kk][ni], acc[mi][ni]);
        __syncthreads();
    }

#pragma unroll
    for (int mi = 0; mi < MI; ++mi)
#pragma unroll
        for (int ni = 0; ni < NI; ++ni) {
            const int colg = n0 + wn * (BN / 2) + ni * 16 + lr;
#pragma unroll
            for (int r = 0; r < 4; ++r) {
                const int rowg = m0 + wm * (BM / 2) + mi * 16 + 4 * g + r;
                const float v = acc[mi][ni][r];
                if constexpr (EPI == 1) {
                    const size_t idx = (size_t)rowg * N + colg;
                    ((float*)outp)[idx] = res[idx] + v;
                } else if constexpr (EPI == 2) {
                    const size_t idx = (size_t)rowg * N + colg;
                    ((__bf16*)outp)[idx] =
                        (__bf16)(0.5f * v * (1.0f + erff(v * 0.70710678118654752f)));
                } else if constexpr (EPI == 3) {
                    const size_t idx = (size_t)rowg * N + colg;
                    ((float*)outp)[idx] += v;
                } else {  // EPI == 4: QKV split
                    __bf16* base = (__bf16*)outp;
                    const int seg = colg >> 10;       // 0=Q, 1=K, 2=V
                    const int cg = colg & 1023;
                    if (seg < 2) {
                        base[(size_t)seg * 4194304 + (size_t)rowg * 1024 + cg] = (__bf16)v;
                    } else {
                        // Vt[b][h][d][t]: b=rowg>>11, t=rowg&2047, h=cg>>6, d=cg&63
                        base[8388608 +
                             ((size_t)((rowg >> 11) * 16 + (cg >> 6)) * 64 + (cg & 63)) * 2048 +
                             (rowg & 2047)] = (__bf16)v;
                    }
                }
            }
        }
}

// ---------------- Flash-style causal attention ------------------------------
// One wave per 16 query rows. Swapped QK^T: S^T = K*Q^T so P is directly the
// PV A-fragment. dh = 64, kv steps of 32. V read from transposed Vt[b][h][d][T].
__global__ __launch_bounds__(256) void attn_kernel(
    const __bf16* __restrict__ Q, const __bf16* __restrict__ Kb,
    const __bf16* __restrict__ Vt, __bf16* __restrict__ ctx)
{
    const int Dm = 1024, T = 2048;
    const int tid = threadIdx.x;
    const int w = tid >> 6, lane = tid & 63;
    const int lr = lane & 15, g = lane >> 4;
    const int blk = blockIdx.x;
    const int qc = blk & 31, h = (blk >> 5) & 15, b = blk >> 9;
    const int qbase = qc * 64 + w * 16;
    const size_t rowoff = (size_t)b * T;
    const __bf16* Qp = Q + rowoff * Dm + h * 64;
    const __bf16* Kp = Kb + rowoff * Dm + h * 64;
    const __bf16* Vtp = Vt + (size_t)(b * 16 + h) * 64 * 2048;

    const bf16x8 qf0 = *(const bf16x8*)&Qp[(size_t)(qbase + lr) * Dm + g * 8];
    const bf16x8 qf1 = *(const bf16x8*)&Qp[(size_t)(qbase + lr) * Dm + 32 + g * 8];

    f32x4 acc[4] = {};
    float m_s = -__builtin_inff(), l_s = 0.0f;

    const int nsteps = (qbase + 16 + 31) >> 5;
    for (int s = 0; s < nsteps; ++s) {
        const int kvb = s * 32;
        const __bf16* k0p = &Kp[(size_t)(kvb + lr) * Dm];
        const __bf16* k1p = &Kp[(size_t)(kvb + 16 + lr) * Dm];
        const bf16x8 kf0a = *(const bf16x8*)&k0p[g * 8];
        const bf16x8 kf0b = *(const bf16x8*)&k0p[32 + g * 8];
        const bf16x8 kf1a = *(const bf16x8*)&k1p[g * 8];
        const bf16x8 kf1b = *(const bf16x8*)&k1p[32 + g * 8];

        const f32x4 zacc = {0.0f, 0.0f, 0.0f, 0.0f};
        f32x4 st0 = MFMA_16x16x32_BF16(kf0a, qf0, zacc);
        st0 = MFMA_16x16x32_BF16(kf0b, qf1, st0);
        f32x4 st1 = MFMA_16x16x32_BF16(kf1a, qf0, zacc);
        st1 = MFMA_16x16x32_BF16(kf1b, qf1, st1);

        const int qg = qbase + lr;
        const bool domask = (kvb + 31 > qbase);
        float s0[4], s1[4];
#pragma unroll
        for (int r = 0; r < 4; ++r) {
            const int kv0 = kvb + 4 * g + r;
            s0[r] = st0[r] * 0.125f;
            s1[r] = st1[r] * 0.125f;
            if (domask) {
                if (kv0 > qg) s0[r] = -__builtin_inff();
                if (kv0 + 16 > qg) s1[r] = -__builtin_inff();
            }
        }
        float tm = fmaxf(fmaxf(fmaxf(s0[0], s0[1]), fmaxf(s0[2], s0[3])),
                         fmaxf(fmaxf(s1[0], s1[1]), fmaxf(s1[2], s1[3])));
        tm = fmaxf(tm, __shfl_xor(tm, 16));
        tm = fmaxf(tm, __shfl_xor(tm, 32));
        const float m_new = fmaxf(m_s, tm);
        const float corr = __expf(m_s - m_new);
        float p0[4], p1[4], rs = 0.0f;
#pragma unroll
        for (int r = 0; r < 4; ++r) {
            p0[r] = __expf(s0[r] - m_new);
            p1[r] = __expf(s1[r] - m_new);
            rs += p0[r] + p1[r];
        }
        rs += __shfl_xor(rs, 16);
        rs += __shfl_xor(rs, 32);
        l_s = l_s * corr + rs;
        m_s = m_new;

        float cr[4];
#pragma unroll
        for (int r = 0; r < 4; ++r) cr[r] = __shfl(corr, 4 * g + r);
#pragma unroll
        for (int ct = 0; ct < 4; ++ct) {
            acc[ct][0] *= cr[0]; acc[ct][1] *= cr[1];
            acc[ct][2] *= cr[2]; acc[ct][3] *= cr[3];
        }

        bf16x8 pa;
#pragma unroll
        for (int r = 0; r < 4; ++r) {
            pa[r] = (__bf16)p0[r];
            pa[4 + r] = (__bf16)p1[r];
        }
#pragma unroll
        for (int ct = 0; ct < 4; ++ct) {
            const __bf16* vrow = Vtp + (size_t)(ct * 16 + lr) * 2048;
            const bf16x4 va = *(const bf16x4*)&vrow[kvb + 4 * g];
            const bf16x4 vb = *(const bf16x4*)&vrow[kvb + 16 + 4 * g];
            bf16x8 vf;
#pragma unroll
            for (int j = 0; j < 4; ++j) { vf[j] = va[j]; vf[4 + j] = vb[j]; }
            acc[ct] = MFMA_16x16x32_BF16(pa, vf, acc[ct]);
        }
    }

    float dn[4];
#pragma unroll
    for (int r = 0; r < 4; ++r) dn[r] = __shfl(l_s, 4 * g + r);
#pragma unroll
    for (int ct = 0; ct < 4; ++ct)
#pragma unroll
        for (int r = 0; r < 4; ++r)
            ctx[(rowoff + qbase + 4 * g + r) * Dm + h * 64 + ct * 16 + lr] =
                (__bf16)(acc[ct][r] / dn[r]);
}

// ---------------------------------------------------------------------------
extern "C" void kernel_launch(void* const* d_in, const int* in_sizes, int n_in,
                              void* d_out, int out_size, void* d_ws, size_t ws_size,
                              hipStream_t stream)
{
    (void)in_sizes; (void)n_in; (void)out_size; (void)ws_size;
    const float* z      = (const float*)d_in[0];
    const float* W_Q    = (const float*)d_in[1];
    const float* W_K    = (const float*)d_in[2];
    const float* W_V    = (const float*)d_in[3];
    const float* W_O    = (const float*)d_in[4];
    const float* W_fc   = (const float*)d_in[5];
    const float* W_proj = (const float*)d_in[6];
    const float* g1     = (const float*)d_in[7];
    const float* g2     = (const float*)d_in[8];
    float* out = (float*)d_out;

    char* ws = (char*)d_ws;
    const size_t MB = (size_t)1 << 20;
    __bf16* WtQKV  = (__bf16*)(ws + 0 * MB);   // [3072][1024]
    __bf16* WtO    = (__bf16*)(ws + 6 * MB);
    __bf16* Wtfc   = (__bf16*)(ws + 8 * MB);
    __bf16* Wtproj = (__bf16*)(ws + 16 * MB);
    __bf16* zn     = (__bf16*)(ws + 24 * MB);  // reused as ctx
    __bf16* Qb     = (__bf16*)(ws + 32 * MB);  // QKV out base; reused as h
    __bf16* Kbuf   = (__bf16*)(ws + 40 * MB);
    __bf16* Vtb    = (__bf16*)(ws + 48 * MB);
    __bf16* ffn1   = (__bf16*)(ws + 40 * MB);  // overlaps K,Vt (dead post-attn)
    __bf16* ctx    = zn;
    __bf16* hb     = Qb;

    const int Tt = 2048, Dm = 1024, Bb = 2, M = Bb * Tt, DFF = 4096;
    const dim3 blk256(256);

    // Weight transpose+convert (WtQ/K/V land contiguous -> WtQKV[3072][1024])
    transconv_kernel<<<dim3(32, 32),  blk256, 0, stream>>>(W_Q, WtQKV,            Dm, Dm);
    transconv_kernel<<<dim3(32, 32),  blk256, 0, stream>>>(W_K, WtQKV + 1048576,  Dm, Dm);
    transconv_kernel<<<dim3(32, 32),  blk256, 0, stream>>>(W_V, WtQKV + 2097152,  Dm, Dm);
    transconv_kernel<<<dim3(32, 32),  blk256, 0, stream>>>(W_O, WtO,  Dm, Dm);
    transconv_kernel<<<dim3(128, 32), blk256, 0, stream>>>(W_fc, Wtfc, Dm, DFF);
    transconv_kernel<<<dim3(32, 128), blk256, 0, stream>>>(W_proj, Wtproj, DFF, Dm);

    // zn = rmsnorm(z, g1)
    rmsnorm_kernel<<<M, blk256, 0, stream>>>(z, g1, zn);

    // Fused QKV: [4096][3072]; epilogue splits Q, K, and transposed Vt
    gemm_bf16<128, 128, 4><<<dim3(24, 32), blk256, 0, stream>>>(
        zn, WtQKV, Qb, nullptr, M, 3072, Dm);

    // attention -> ctx
    attn_kernel<<<1024, blk256, 0, stream>>>(Qb, Kbuf, Vtb, ctx);

    // z2 = z + ctx @ W_O  -> d_out (fp32)
    gemm_bf16<128, 64, 1><<<dim3(16, 32), blk256, 0, stream>>>(
        ctx, WtO, out, z, M, Dm, Dm);

    // h = rmsnorm(z2, g2)
    rmsnorm_kernel<<<M, blk256, 0, stream>>>(out, g2, hb);

    // ffn1 = gelu_erf(h @ W_fc)
    gemm_bf16<128, 128, 2><<<dim3(32, 32), blk256, 0, stream>>>(
        hb, Wtfc, ffn1, nullptr, M, DFF, Dm);

    // d_out += ffn1 @ W_proj
    gemm_bf16<128, 64, 3><<<dim3(16, 32), blk256, 0, stream>>>(
        ffn1, Wtproj, out, nullptr, M, Dm, DFF);
}

// Round 3
// 328.393 us; speedup vs baseline: 1.8140x; 1.8140x over previous
//
#include <hip/hip_runtime.h>
#include <hip/hip_bf16.h>
#include <math.h>

// ---------------------------------------------------------------------------
// GPT block on MI355X (gfx950). bf16 MFMA compute, fp32 accumulate.
// Workspace layout (MB = 1<<20), total 72 MB:
//   [ 0, 6)  WtQKV  bf16 [3072][1024]  (W_Q,W_K,W_V transposed, contiguous)
//   [ 6, 8)  WtO    bf16 [1024][1024]
//   [ 8,16)  Wtfc   bf16 [4096][1024]
//   [16,24)  Wtproj bf16 [1024][4096]
//   [24,32)  zn / ctx   bf16 [4096][1024]
//   [32,40)  Q / h      bf16 [4096][1024]
//   [40,48)  K          bf16 [4096][1024]
//   [48,56)  Vt         bf16 [32][64][2048]  (V transposed per (b,h))
//   [40,72)  ffn1       bf16 [4096][4096]  (overlaps K,Vt — dead after attn)
// d_out doubles as z2 (fp32): O-proj writes z2 = z + attn; proj does +=.
// ---------------------------------------------------------------------------

typedef __bf16 bf16x8 __attribute__((ext_vector_type(8)));
typedef __bf16 bf16x4 __attribute__((ext_vector_type(4)));
typedef float  f32x4  __attribute__((ext_vector_type(4)));

#define MFMA_16x16x32_BF16(A, B, C) __builtin_amdgcn_mfma_f32_16x16x32_bf16((A), (B), (C), 0, 0, 0)

#define GLDS16(g, l) __builtin_amdgcn_global_load_lds( \
    (const __attribute__((address_space(1))) void*)(g), \
    (__attribute__((address_space(3))) void*)(l), 16, 0, 0)

// ---------------- transpose + fp32->bf16 convert:  src[K][N] -> dst[N][K] ----
__global__ __launch_bounds__(256) void transconv_kernel(
    const float* __restrict__ src, __bf16* __restrict__ dst, int K, int N)
{
    __shared__ float tile[32][33];
    const int n0 = blockIdx.x * 32, k0 = blockIdx.y * 32;
    const int c = threadIdx.x & 31, r = threadIdx.x >> 5;
#pragma unroll
    for (int i = 0; i < 4; ++i)
        tile[r + 8 * i][c] = src[(size_t)(k0 + r + 8 * i) * N + n0 + c];
    __syncthreads();
#pragma unroll
    for (int i = 0; i < 4; ++i)
        dst[(size_t)(n0 + r + 8 * i) * K + k0 + c] = (__bf16)tile[c][r + 8 * i];
}

// ---------------- RMSNorm: fp32 [M][1024] -> bf16 [M][1024] -----------------
__global__ __launch_bounds__(256) void rmsnorm_kernel(
    const float* __restrict__ x, const float* __restrict__ gain,
    __bf16* __restrict__ out)
{
    const int row = blockIdx.x, t = threadIdx.x;
    const float4 v = ((const float4*)(x + (size_t)row * 1024))[t];
    float ss = v.x * v.x + v.y * v.y + v.z * v.z + v.w * v.w;
#pragma unroll
    for (int m = 1; m < 64; m <<= 1) ss += __shfl_xor(ss, m);
    __shared__ float red[4];
    const int wid = t >> 6, lane = t & 63;
    if (lane == 0) red[wid] = ss;
    __syncthreads();
    const float tot = red[0] + red[1] + red[2] + red[3];
    const float inv = rsqrtf(tot * (1.0f / 1024.0f) + 1e-5f);
    const float4 gv = ((const float4*)gain)[t];
    __bf16* o = out + (size_t)row * 1024 + t * 4;
    o[0] = (__bf16)(v.x * inv * gv.x);
    o[1] = (__bf16)(v.y * inv * gv.y);
    o[2] = (__bf16)(v.z * inv * gv.z);
    o[3] = (__bf16)(v.w * inv * gv.w);
}

// ---------------- GEMM: C[M][N] = A[M][K] * Bt[N][K]^T, bf16 MFMA ----------
// m97 structure: global_load_lds width 16, linear LDS [tile][64], BK=64.
// EPI: 1 = out_f32 = res + acc; 2 = store bf16 gelu_erf(acc); 3 = out_f32 += acc
// EPI: 4 = fused QKV split: outp = Q base; K at +4M elems; Vt at +8M elems
template <int BM, int BN, int EPI>
__global__ __launch_bounds__(256) void gemm_bf16(
    const __bf16* __restrict__ A, const __bf16* __restrict__ Bt,
    void* __restrict__ outp, const float* __restrict__ res,
    int M, int N, int K)
{
    __shared__ __bf16 As[BM * 64];
    __shared__ __bf16 Bs[BN * 64];
    const int tid = threadIdx.x;
    const int m0 = blockIdx.y * BM, n0 = blockIdx.x * BN;
    const int lane = tid & 63, w = tid >> 6;
    const int wm = w >> 1, wn = w & 1;
    const int lr = lane & 15, g = lane >> 4;
    const int srow = lane >> 3, scol = (lane & 7) * 8;  // staging map

    constexpr int MI = BM / 32, NI = BN / 32;
    f32x4 acc[MI][NI] = {};

    const __bf16* Abase = A + (size_t)m0 * K;
    const __bf16* Bbase = Bt + (size_t)n0 * K;

    for (int kb = 0; kb < K; kb += 64) {
#pragma unroll
        for (int j = 0; j < BM / 32; ++j) {
            const int s = j * 4 + w;
            GLDS16(Abase + (size_t)(s * 8 + srow) * K + kb + scol, &As[s * 512]);
        }
#pragma unroll
        for (int j = 0; j < BN / 32; ++j) {
            const int s = j * 4 + w;
            GLDS16(Bbase + (size_t)(s * 8 + srow) * K + kb + scol, &Bs[s * 512]);
        }
        __syncthreads();

        bf16x8 af[2][MI], bfr[2][NI];
#pragma unroll
        for (int kk = 0; kk < 2; ++kk) {
#pragma unroll
            for (int i = 0; i < MI; ++i)
                af[kk][i] = *(const bf16x8*)&As[(wm * (BM / 2) + i * 16 + lr) * 64 + kk * 32 + g * 8];
#pragma unroll
            for (int i = 0; i < NI; ++i)
                bfr[kk][i] = *(const bf16x8*)&Bs[(wn * (BN / 2) + i * 16 + lr) * 64 + kk * 32 + g * 8];
        }
#pragma unroll
        for (int kk = 0; kk < 2; ++kk)
#pragma unroll
            for (int mi = 0; mi < MI; ++mi)
#pragma unroll
                for (int ni = 0; ni < NI; ++ni)
                    acc[mi][ni] = MFMA_16x16x32_BF16(af[kk][mi], bfr[kk][ni], acc[mi][ni]);
        __syncthreads();
    }

#pragma unroll
    for (int mi = 0; mi < MI; ++mi)
#pragma unroll
        for (int ni = 0; ni < NI; ++ni) {
            const int colg = n0 + wn * (BN / 2) + ni * 16 + lr;
#pragma unroll
            for (int r = 0; r < 4; ++r) {
                const int rowg = m0 + wm * (BM / 2) + mi * 16 + 4 * g + r;
                const float v = acc[mi][ni][r];
                if constexpr (EPI == 1) {
                    const size_t idx = (size_t)rowg * N + colg;
                    ((float*)outp)[idx] = res[idx] + v;
                } else if constexpr (EPI == 2) {
                    const size_t idx = (size_t)rowg * N + colg;
                    ((__bf16*)outp)[idx] =
                        (__bf16)(0.5f * v * (1.0f + erff(v * 0.70710678118654752f)));
                } else if constexpr (EPI == 3) {
                    const size_t idx = (size_t)rowg * N + colg;
                    ((float*)outp)[idx] += v;
                } else {  // EPI == 4: QKV split
                    __bf16* base = (__bf16*)outp;
                    const int seg = colg >> 10;       // 0=Q, 1=K, 2=V
                    const int cg = colg & 1023;
                    if (seg < 2) {
                        base[(size_t)seg * 4194304 + (size_t)rowg * 1024 + cg] = (__bf16)v;
                    } else {
                        // Vt[b][h][d][t]: b=rowg>>11, t=rowg&2047, h=cg>>6, d=cg&63
                        base[8388608 +
                             ((size_t)((rowg >> 11) * 16 + (cg >> 6)) * 64 + (cg & 63)) * 2048 +
                             (rowg & 2047)] = (__bf16)v;
                    }
                }
            }
        }
}

// ---------------- Flash-style causal attention (LDS-staged, dbuf) -----------
// Grid: blockIdx.x = qc*32 + bh  (qc = 64-row q-chunk, bh = b*16+h) so that
// same-CU blocks (stride 256 apart) get different qc -> balanced work.
// Block: 4 waves, each owns 16 q-rows. KV steps of 64, K and Vt tiles staged
// into LDS via global_load_lds (linear dest) with T2 XOR swizzle applied by
// pre-swizzling the global source chunk; reads apply the same XOR.
__global__ __launch_bounds__(256) void attn_kernel(
    const __bf16* __restrict__ Q, const __bf16* __restrict__ Kb,
    const __bf16* __restrict__ Vt, __bf16* __restrict__ ctx)
{
    const int Dm = 1024, T = 2048;
    const int tid = threadIdx.x;
    const int w = tid >> 6, lane = tid & 63;
    const int lr = lane & 15, g = lane >> 4;
    const int bx = blockIdx.x;
    const int qc = bx >> 5, bh = bx & 31, b = bh >> 4, h = bh & 15;
    const int qbase = qc * 64 + w * 16;
    const size_t rowoff = (size_t)b * T;
    const __bf16* Qp = Q + rowoff * Dm + h * 64;
    const __bf16* Kp = Kb + rowoff * Dm + h * 64;        // row t, stride 1024
    const __bf16* Vtp = Vt + (size_t)bh * 64 * 2048;     // row d, stride 2048

    __shared__ __bf16 Ks[2][64 * 64];
    __shared__ __bf16 Vs[2][64 * 64];

    // Q fragments (hoisted)
    const bf16x8 qf0 = *(const bf16x8*)&Qp[(size_t)(qbase + lr) * Dm + g * 8];
    const bf16x8 qf1 = *(const bf16x8*)&Qp[(size_t)(qbase + lr) * Dm + 32 + g * 8];

    // staging lane map: lane l -> tile row (l>>3), LDS chunk (l&7);
    // global chunk pre-swizzled so LDS[row][c] = G[row][c ^ (row&7)]
    const int srow = lane >> 3;
    const int schunk = (lane & 7) ^ srow;

    f32x4 acc[4] = {};
    float m_s = -__builtin_inff(), l_s = 0.0f;
    const int nsteps = qc + 1;
    const f32x4 zacc = {0.0f, 0.0f, 0.0f, 0.0f};
    const int xr = (lr & 7) << 3;   // read-side XOR (element units)
    const int qg = qbase + lr;

    // prologue stage of tile 0
#pragma unroll
    for (int j = 0; j < 2; ++j) {
        const int row = j * 32 + w * 8 + srow;
        GLDS16(Kp + (size_t)row * Dm + schunk * 8, &Ks[0][(j * 32 + w * 8) * 64]);
        GLDS16(Vtp + (size_t)row * T + schunk * 8, &Vs[0][(j * 32 + w * 8) * 64]);
    }
    __syncthreads();

    for (int t = 0; t < nsteps; ++t) {
        const int kvb = t * 64, cur = t & 1;
        if (t + 1 < nsteps) {
#pragma unroll
            for (int j = 0; j < 2; ++j) {
                const int row = j * 32 + w * 8 + srow;
                GLDS16(Kp + (size_t)(kvb + 64 + row) * Dm + schunk * 8,
                       &Ks[cur ^ 1][(j * 32 + w * 8) * 64]);
                GLDS16(Vtp + (size_t)row * T + kvb + 64 + schunk * 8,
                       &Vs[cur ^ 1][(j * 32 + w * 8) * 64]);
            }
        }

        // ---- QK^T: four 16-kv sub-tiles ----
        float sv[4][4];
#pragma unroll
        for (int s4 = 0; s4 < 4; ++s4) {
            const int kv0 = kvb + s4 * 16;
            if (kv0 <= qbase + 15) {
                const int row = s4 * 16 + lr;
                const bf16x8 kfa = *(const bf16x8*)&Ks[cur][row * 64 + ((g * 8) ^ xr)];
                const bf16x8 kfb = *(const bf16x8*)&Ks[cur][row * 64 + ((32 + g * 8) ^ xr)];
                f32x4 st = MFMA_16x16x32_BF16(kfa, qf0, zacc);
                st = MFMA_16x16x32_BF16(kfb, qf1, st);
                const bool domask = (kv0 + 15 > qbase);
#pragma unroll
                for (int r = 0; r < 4; ++r) {
                    float x = st[r] * 0.125f;
                    if (domask && (kv0 + 4 * g + r > qg)) x = -__builtin_inff();
                    sv[s4][r] = x;
                }
            } else {
#pragma unroll
                for (int r = 0; r < 4; ++r) sv[s4][r] = -__builtin_inff();
            }
        }

        // ---- joint online softmax over 64 kv ----
        float tm = sv[0][0];
#pragma unroll
        for (int s4 = 0; s4 < 4; ++s4)
#pragma unroll
            for (int r = 0; r < 4; ++r) tm = fmaxf(tm, sv[s4][r]);
        tm = fmaxf(tm, __shfl_xor(tm, 16));
        tm = fmaxf(tm, __shfl_xor(tm, 32));
        const float m_new = fmaxf(m_s, tm);
        const float corr = __expf(m_s - m_new);
        float rs = 0.0f;
#pragma unroll
        for (int s4 = 0; s4 < 4; ++s4)
#pragma unroll
            for (int r = 0; r < 4; ++r) {
                sv[s4][r] = __expf(sv[s4][r] - m_new);
                rs += sv[s4][r];
            }
        rs += __shfl_xor(rs, 16);
        rs += __shfl_xor(rs, 32);
        l_s = l_s * corr + rs;
        m_s = m_new;

        float cr[4];
#pragma unroll
        for (int r = 0; r < 4; ++r) cr[r] = __shfl(corr, 4 * g + r);
#pragma unroll
        for (int ct = 0; ct < 4; ++ct) {
            acc[ct][0] *= cr[0]; acc[ct][1] *= cr[1];
            acc[ct][2] *= cr[2]; acc[ct][3] *= cr[3];
        }

        // ---- PV ----
        bf16x8 pa0, pa1;
#pragma unroll
        for (int r = 0; r < 4; ++r) {
            pa0[r] = (__bf16)sv[0][r];
            pa0[4 + r] = (__bf16)sv[1][r];
            pa1[r] = (__bf16)sv[2][r];
            pa1[4 + r] = (__bf16)sv[3][r];
        }
        const bool liveB = (kvb + 32 <= qbase + 15);
#pragma unroll
        for (int ct = 0; ct < 4; ++ct) {
            const __bf16* vrow = &Vs[cur][(ct * 16 + lr) * 64];
            const bf16x4 va0 = *(const bf16x4*)&vrow[(4 * g) ^ xr];
            const bf16x4 va1 = *(const bf16x4*)&vrow[(16 + 4 * g) ^ xr];
            bf16x8 vf;
#pragma unroll
            for (int j = 0; j < 4; ++j) { vf[j] = va0[j]; vf[4 + j] = va1[j]; }
            acc[ct] = MFMA_16x16x32_BF16(pa0, vf, acc[ct]);
            if (liveB) {
                const bf16x4 vb0 = *(const bf16x4*)&vrow[(32 + 4 * g) ^ xr];
                const bf16x4 vb1 = *(const bf16x4*)&vrow[(48 + 4 * g) ^ xr];
                bf16x8 vf2;
#pragma unroll
                for (int j = 0; j < 4; ++j) { vf2[j] = vb0[j]; vf2[4 + j] = vb1[j]; }
                acc[ct] = MFMA_16x16x32_BF16(pa1, vf2, acc[ct]);
            }
        }
        __syncthreads();
    }

    float dn[4];
#pragma unroll
    for (int r = 0; r < 4; ++r) dn[r] = __shfl(l_s, 4 * g + r);
#pragma unroll
    for (int ct = 0; ct < 4; ++ct)
#pragma unroll
        for (int r = 0; r < 4; ++r)
            ctx[(rowoff + qbase + 4 * g + r) * Dm + h * 64 + ct * 16 + lr] =
                (__bf16)(acc[ct][r] / dn[r]);
}

// ---------------------------------------------------------------------------
extern "C" void kernel_launch(void* const* d_in, const int* in_sizes, int n_in,
                              void* d_out, int out_size, void* d_ws, size_t ws_size,
                              hipStream_t stream)
{
    (void)in_sizes; (void)n_in; (void)out_size; (void)ws_size;
    const float* z      = (const float*)d_in[0];
    const float* W_Q    = (const float*)d_in[1];
    const float* W_K    = (const float*)d_in[2];
    const float* W_V    = (const float*)d_in[3];
    const float* W_O    = (const float*)d_in[4];
    const float* W_fc   = (const float*)d_in[5];
    const float* W_proj = (const float*)d_in[6];
    const float* g1     = (const float*)d_in[7];
    const float* g2     = (const float*)d_in[8];
    float* out = (float*)d_out;

    char* ws = (char*)d_ws;
    const size_t MB = (size_t)1 << 20;
    __bf16* WtQKV  = (__bf16*)(ws + 0 * MB);   // [3072][1024]
    __bf16* WtO    = (__bf16*)(ws + 6 * MB);
    __bf16* Wtfc   = (__bf16*)(ws + 8 * MB);
    __bf16* Wtproj = (__bf16*)(ws + 16 * MB);
    __bf16* zn     = (__bf16*)(ws + 24 * MB);  // reused as ctx
    __bf16* Qb     = (__bf16*)(ws + 32 * MB);  // QKV out base; reused as h
    __bf16* Kbuf   = (__bf16*)(ws + 40 * MB);
    __bf16* Vtb    = (__bf16*)(ws + 48 * MB);
    __bf16* ffn1   = (__bf16*)(ws + 40 * MB);  // overlaps K,Vt (dead post-attn)
    __bf16* ctx    = zn;
    __bf16* hb     = Qb;

    const int Tt = 2048, Dm = 1024, Bb = 2, M = Bb * Tt, DFF = 4096;
    const dim3 blk256(256);

    // Weight transpose+convert (WtQ/K/V land contiguous -> WtQKV[3072][1024])
    transconv_kernel<<<dim3(32, 32),  blk256, 0, stream>>>(W_Q, WtQKV,            Dm, Dm);
    transconv_kernel<<<dim3(32, 32),  blk256, 0, stream>>>(W_K, WtQKV + 1048576,  Dm, Dm);
    transconv_kernel<<<dim3(32, 32),  blk256, 0, stream>>>(W_V, WtQKV + 2097152,  Dm, Dm);
    transconv_kernel<<<dim3(32, 32),  blk256, 0, stream>>>(W_O, WtO,  Dm, Dm);
    transconv_kernel<<<dim3(128, 32), blk256, 0, stream>>>(W_fc, Wtfc, Dm, DFF);
    transconv_kernel<<<dim3(32, 128), blk256, 0, stream>>>(W_proj, Wtproj, DFF, Dm);

    // zn = rmsnorm(z, g1)
    rmsnorm_kernel<<<M, blk256, 0, stream>>>(z, g1, zn);

    // Fused QKV: [4096][3072]; epilogue splits Q, K, and transposed Vt
    gemm_bf16<128, 128, 4><<<dim3(24, 32), blk256, 0, stream>>>(
        zn, WtQKV, Qb, nullptr, M, 3072, Dm);

    // attention -> ctx
    attn_kernel<<<1024, blk256, 0, stream>>>(Qb, Kbuf, Vtb, ctx);

    // z2 = z + ctx @ W_O  -> d_out (fp32)
    gemm_bf16<128, 64, 1><<<dim3(16, 32), blk256, 0, stream>>>(
        ctx, WtO, out, z, M, Dm, Dm);

    // h = rmsnorm(z2, g2)
    rmsnorm_kernel<<<M, blk256, 0, stream>>>(out, g2, hb);

    // ffn1 = gelu_erf(h @ W_fc)
    gemm_bf16<128, 128, 2><<<dim3(32, 32), blk256, 0, stream>>>(
        hb, Wtfc, ffn1, nullptr, M, DFF, Dm);

    // d_out += ffn1 @ W_proj
    gemm_bf16<128, 64, 3><<<dim3(16, 32), blk256, 0, stream>>>(
        ffn1, Wtproj, out, nullptr, M, Dm, DFF);
}

// Round 4
// 292.409 us; speedup vs baseline: 2.0372x; 1.1231x over previous
//
#include <hip/hip_runtime.h>
#include <hip/hip_bf16.h>
#include <math.h>

// ---------------------------------------------------------------------------
// GPT block on MI355X (gfx950). bf16 MFMA compute, fp32 accumulate.
// Workspace layout (MB = 1<<20), total 72 MB:
//   [ 0, 6)  WtQKV  bf16 [3072][1024]  (W_Q,W_K,W_V transposed, contiguous)
//   [ 6, 8)  WtO    bf16 [1024][1024]
//   [ 8,16)  Wtfc   bf16 [4096][1024]
//   [16,24)  Wtproj bf16 [1024][4096]
//   [24,32)  zn / ctx   bf16 [4096][1024]
//   [32,40)  Q / h      bf16 [4096][1024]
//   [40,48)  K          bf16 [4096][1024]
//   [48,56)  Vt         bf16 [32][64][2048]  (V transposed per (b,h))
//   [40,72)  ffn1       bf16 [4096][4096]  (overlaps K,Vt — dead after attn)
// d_out doubles as z2 (fp32): O-proj writes z2 = z + attn; proj does +=.
// GEMM LDS tiles use T2 XOR swizzle: linear global_load_lds dest, source
// chunk pre-swizzled by (row&7), ds_read chunk XOR'd the same way.
// ---------------------------------------------------------------------------

typedef __bf16 bf16x8 __attribute__((ext_vector_type(8)));
typedef __bf16 bf16x4 __attribute__((ext_vector_type(4)));
typedef float  f32x4  __attribute__((ext_vector_type(4)));

#define MFMA_16x16x32_BF16(A, B, C) __builtin_amdgcn_mfma_f32_16x16x32_bf16((A), (B), (C), 0, 0, 0)

#define GLDS16(g, l) __builtin_amdgcn_global_load_lds( \
    (const __attribute__((address_space(1))) void*)(g), \
    (__attribute__((address_space(3))) void*)(l), 16, 0, 0)

// ---------------- fused transpose + fp32->bf16 convert for all 6 weights ----
// src[K][N] -> dst[N][K] in 32x32 tiles. Grid ids:
//   [0,4096)      W_Q/W_K/W_V/W_O (1024 tiles each, nx=32)
//   [4096,8192)   W_fc  (nx=128)
//   [8192,12288)  W_proj (nx=32)
__global__ __launch_bounds__(256) void transconv_all_kernel(
    const float* __restrict__ W_Q, const float* __restrict__ W_K,
    const float* __restrict__ W_V, const float* __restrict__ W_O,
    const float* __restrict__ W_fc, const float* __restrict__ W_proj,
    __bf16* __restrict__ WtQKV, __bf16* __restrict__ WtO,
    __bf16* __restrict__ Wtfc, __bf16* __restrict__ Wtproj)
{
    const int id = blockIdx.x;
    const float* src;
    __bf16* dst;
    int K, N, nx, t;
    if (id < 4096) {
        const int wsel = id >> 10;
        t = id & 1023;
        src = (wsel == 0) ? W_Q : (wsel == 1) ? W_K : (wsel == 2) ? W_V : W_O;
        dst = (wsel < 3) ? (WtQKV + (size_t)wsel * 1048576) : WtO;
        K = 1024; N = 1024; nx = 32;
    } else if (id < 8192) {
        t = id - 4096; src = W_fc; dst = Wtfc; K = 1024; N = 4096; nx = 128;
    } else {
        t = id - 8192; src = W_proj; dst = Wtproj; K = 4096; N = 1024; nx = 32;
    }
    const int n0 = (t % nx) * 32, k0 = (t / nx) * 32;

    __shared__ float tile[32][33];
    const int c = threadIdx.x & 31, r = threadIdx.x >> 5;
#pragma unroll
    for (int i = 0; i < 4; ++i)
        tile[r + 8 * i][c] = src[(size_t)(k0 + r + 8 * i) * N + n0 + c];
    __syncthreads();
#pragma unroll
    for (int i = 0; i < 4; ++i)
        dst[(size_t)(n0 + r + 8 * i) * K + k0 + c] = (__bf16)tile[c][r + 8 * i];
}

// ---------------- RMSNorm: fp32 [M][1024] -> bf16 [M][1024] -----------------
__global__ __launch_bounds__(256) void rmsnorm_kernel(
    const float* __restrict__ x, const float* __restrict__ gain,
    __bf16* __restrict__ out)
{
    const int row = blockIdx.x, t = threadIdx.x;
    const float4 v = ((const float4*)(x + (size_t)row * 1024))[t];
    float ss = v.x * v.x + v.y * v.y + v.z * v.z + v.w * v.w;
#pragma unroll
    for (int m = 1; m < 64; m <<= 1) ss += __shfl_xor(ss, m);
    __shared__ float red[4];
    const int wid = t >> 6, lane = t & 63;
    if (lane == 0) red[wid] = ss;
    __syncthreads();
    const float tot = red[0] + red[1] + red[2] + red[3];
    const float inv = rsqrtf(tot * (1.0f / 1024.0f) + 1e-5f);
    const float4 gv = ((const float4*)gain)[t];
    __bf16* o = out + (size_t)row * 1024 + t * 4;
    o[0] = (__bf16)(v.x * inv * gv.x);
    o[1] = (__bf16)(v.y * inv * gv.y);
    o[2] = (__bf16)(v.z * inv * gv.z);
    o[3] = (__bf16)(v.w * inv * gv.w);
}

// ---------------- GEMM: C[M][N] = A[M][K] * Bt[N][K]^T, bf16 MFMA ----------
// m97 structure + T2 LDS XOR swizzle + T1 XCD-aware block remap.
// EPI: 1 = out_f32 = res + acc; 2 = store bf16 gelu_erf(acc); 3 = out_f32 += acc
// EPI: 4 = fused QKV split: outp = Q base; K at +4M elems; Vt at +8M elems
template <int BM, int BN, int EPI>
__global__ __launch_bounds__(256) void gemm_bf16(
    const __bf16* __restrict__ A, const __bf16* __restrict__ Bt,
    void* __restrict__ outp, const float* __restrict__ res,
    int M, int N, int K)
{
    __shared__ __bf16 As[BM * 64];
    __shared__ __bf16 Bs[BN * 64];
    const int tid = threadIdx.x;

    // T1: bijective XCD-contiguous remap (all launches have nwg % 8 == 0)
    const int gx = gridDim.x, nwg = gx * gridDim.y;
    int bid = blockIdx.y * gx + blockIdx.x;
    if ((nwg & 7) == 0) bid = (bid & 7) * (nwg >> 3) + (bid >> 3);
    const int m0 = (bid / gx) * BM, n0 = (bid % gx) * BN;

    const int lane = tid & 63, w = tid >> 6;
    const int wm = w >> 1, wn = w & 1;
    const int lr = lane & 15, g = lane >> 4;
    const int srow = lane >> 3;                       // staging row-in-8
    const int scol = ((lane & 7) ^ srow) * 8;         // pre-swizzled source chunk
    const int xr8 = lr & 7;                           // read-side chunk XOR

    constexpr int MI = BM / 32, NI = BN / 32;
    f32x4 acc[MI][NI] = {};

    const __bf16* Abase = A + (size_t)m0 * K;
    const __bf16* Bbase = Bt + (size_t)n0 * K;

    for (int kb = 0; kb < K; kb += 64) {
#pragma unroll
        for (int j = 0; j < BM / 32; ++j) {
            const int s = j * 4 + w;
            GLDS16(Abase + (size_t)(s * 8 + srow) * K + kb + scol, &As[s * 512]);
        }
#pragma unroll
        for (int j = 0; j < BN / 32; ++j) {
            const int s = j * 4 + w;
            GLDS16(Bbase + (size_t)(s * 8 + srow) * K + kb + scol, &Bs[s * 512]);
        }
        __syncthreads();

        bf16x8 af[2][MI], bfr[2][NI];
#pragma unroll
        for (int kk = 0; kk < 2; ++kk) {
#pragma unroll
            for (int i = 0; i < MI; ++i)
                af[kk][i] = *(const bf16x8*)
                    &As[(wm * (BM / 2) + i * 16 + lr) * 64 + (((kk * 4 + g) ^ xr8) << 3)];
#pragma unroll
            for (int i = 0; i < NI; ++i)
                bfr[kk][i] = *(const bf16x8*)
                    &Bs[(wn * (BN / 2) + i * 16 + lr) * 64 + (((kk * 4 + g) ^ xr8) << 3)];
        }
#pragma unroll
        for (int kk = 0; kk < 2; ++kk)
#pragma unroll
            for (int mi = 0; mi < MI; ++mi)
#pragma unroll
                for (int ni = 0; ni < NI; ++ni)
                    acc[mi][ni] = MFMA_16x16x32_BF16(af[kk][mi], bfr[kk][ni], acc[mi][ni]);
        __syncthreads();
    }

#pragma unroll
    for (int mi = 0; mi < MI; ++mi)
#pragma unroll
        for (int ni = 0; ni < NI; ++ni) {
            const int colg = n0 + wn * (BN / 2) + ni * 16 + lr;
#pragma unroll
            for (int r = 0; r < 4; ++r) {
                const int rowg = m0 + wm * (BM / 2) + mi * 16 + 4 * g + r;
                const float v = acc[mi][ni][r];
                if constexpr (EPI == 1) {
                    const size_t idx = (size_t)rowg * N + colg;
                    ((float*)outp)[idx] = res[idx] + v;
                } else if constexpr (EPI == 2) {
                    const size_t idx = (size_t)rowg * N + colg;
                    ((__bf16*)outp)[idx] =
                        (__bf16)(0.5f * v * (1.0f + erff(v * 0.70710678118654752f)));
                } else if constexpr (EPI == 3) {
                    const size_t idx = (size_t)rowg * N + colg;
                    ((float*)outp)[idx] += v;
                } else {  // EPI == 4: QKV split
                    __bf16* base = (__bf16*)outp;
                    const int seg = colg >> 10;       // 0=Q, 1=K, 2=V
                    const int cg = colg & 1023;
                    if (seg < 2) {
                        base[(size_t)seg * 4194304 + (size_t)rowg * 1024 + cg] = (__bf16)v;
                    } else {
                        // Vt[b][h][d][t]: b=rowg>>11, t=rowg&2047, h=cg>>6, d=cg&63
                        base[8388608 +
                             ((size_t)((rowg >> 11) * 16 + (cg >> 6)) * 64 + (cg & 63)) * 2048 +
                             (rowg & 2047)] = (__bf16)v;
                    }
                }
            }
        }
}

// ---------------- Flash-style causal attention (LDS-staged, dbuf) -----------
// Grid: blockIdx.x = qc*32 + bh  (qc = 64-row q-chunk, bh = b*16+h) so that
// same-CU blocks (stride 256 apart) get different qc -> balanced work.
__global__ __launch_bounds__(256) void attn_kernel(
    const __bf16* __restrict__ Q, const __bf16* __restrict__ Kb,
    const __bf16* __restrict__ Vt, __bf16* __restrict__ ctx)
{
    const int Dm = 1024, T = 2048;
    const int tid = threadIdx.x;
    const int w = tid >> 6, lane = tid & 63;
    const int lr = lane & 15, g = lane >> 4;
    const int bx = blockIdx.x;
    const int qc = bx >> 5, bh = bx & 31, b = bh >> 4, h = bh & 15;
    const int qbase = qc * 64 + w * 16;
    const size_t rowoff = (size_t)b * T;
    const __bf16* Qp = Q + rowoff * Dm + h * 64;
    const __bf16* Kp = Kb + rowoff * Dm + h * 64;        // row t, stride 1024
    const __bf16* Vtp = Vt + (size_t)bh * 64 * 2048;     // row d, stride 2048

    __shared__ __bf16 Ks[2][64 * 64];
    __shared__ __bf16 Vs[2][64 * 64];

    const bf16x8 qf0 = *(const bf16x8*)&Qp[(size_t)(qbase + lr) * Dm + g * 8];
    const bf16x8 qf1 = *(const bf16x8*)&Qp[(size_t)(qbase + lr) * Dm + 32 + g * 8];

    const int srow = lane >> 3;
    const int schunk = (lane & 7) ^ srow;

    f32x4 acc[4] = {};
    float m_s = -__builtin_inff(), l_s = 0.0f;
    const int nsteps = qc + 1;
    const f32x4 zacc = {0.0f, 0.0f, 0.0f, 0.0f};
    const int xr = (lr & 7) << 3;
    const int qg = qbase + lr;

#pragma unroll
    for (int j = 0; j < 2; ++j) {
        const int row = j * 32 + w * 8 + srow;
        GLDS16(Kp + (size_t)row * Dm + schunk * 8, &Ks[0][(j * 32 + w * 8) * 64]);
        GLDS16(Vtp + (size_t)row * T + schunk * 8, &Vs[0][(j * 32 + w * 8) * 64]);
    }
    __syncthreads();

    for (int t = 0; t < nsteps; ++t) {
        const int kvb = t * 64, cur = t & 1;
        if (t + 1 < nsteps) {
#pragma unroll
            for (int j = 0; j < 2; ++j) {
                const int row = j * 32 + w * 8 + srow;
                GLDS16(Kp + (size_t)(kvb + 64 + row) * Dm + schunk * 8,
                       &Ks[cur ^ 1][(j * 32 + w * 8) * 64]);
                GLDS16(Vtp + (size_t)row * T + kvb + 64 + schunk * 8,
                       &Vs[cur ^ 1][(j * 32 + w * 8) * 64]);
            }
        }

        float sv[4][4];
#pragma unroll
        for (int s4 = 0; s4 < 4; ++s4) {
            const int kv0 = kvb + s4 * 16;
            if (kv0 <= qbase + 15) {
                const int row = s4 * 16 + lr;
                const bf16x8 kfa = *(const bf16x8*)&Ks[cur][row * 64 + ((g * 8) ^ xr)];
                const bf16x8 kfb = *(const bf16x8*)&Ks[cur][row * 64 + ((32 + g * 8) ^ xr)];
                f32x4 st = MFMA_16x16x32_BF16(kfa, qf0, zacc);
                st = MFMA_16x16x32_BF16(kfb, qf1, st);
                const bool domask = (kv0 + 15 > qbase);
#pragma unroll
                for (int r = 0; r < 4; ++r) {
                    float x = st[r] * 0.125f;
                    if (domask && (kv0 + 4 * g + r > qg)) x = -__builtin_inff();
                    sv[s4][r] = x;
                }
            } else {
#pragma unroll
                for (int r = 0; r < 4; ++r) sv[s4][r] = -__builtin_inff();
            }
        }

        float tm = sv[0][0];
#pragma unroll
        for (int s4 = 0; s4 < 4; ++s4)
#pragma unroll
            for (int r = 0; r < 4; ++r) tm = fmaxf(tm, sv[s4][r]);
        tm = fmaxf(tm, __shfl_xor(tm, 16));
        tm = fmaxf(tm, __shfl_xor(tm, 32));
        const float m_new = fmaxf(m_s, tm);
        const float corr = __expf(m_s - m_new);
        float rs = 0.0f;
#pragma unroll
        for (int s4 = 0; s4 < 4; ++s4)
#pragma unroll
            for (int r = 0; r < 4; ++r) {
                sv[s4][r] = __expf(sv[s4][r] - m_new);
                rs += sv[s4][r];
            }
        rs += __shfl_xor(rs, 16);
        rs += __shfl_xor(rs, 32);
        l_s = l_s * corr + rs;
        m_s = m_new;

        float cr[4];
#pragma unroll
        for (int r = 0; r < 4; ++r) cr[r] = __shfl(corr, 4 * g + r);
#pragma unroll
        for (int ct = 0; ct < 4; ++ct) {
            acc[ct][0] *= cr[0]; acc[ct][1] *= cr[1];
            acc[ct][2] *= cr[2]; acc[ct][3] *= cr[3];
        }

        bf16x8 pa0, pa1;
#pragma unroll
        for (int r = 0; r < 4; ++r) {
            pa0[r] = (__bf16)sv[0][r];
            pa0[4 + r] = (__bf16)sv[1][r];
            pa1[r] = (__bf16)sv[2][r];
            pa1[4 + r] = (__bf16)sv[3][r];
        }
        const bool liveB = (kvb + 32 <= qbase + 15);
#pragma unroll
        for (int ct = 0; ct < 4; ++ct) {
            const __bf16* vrow = &Vs[cur][(ct * 16 + lr) * 64];
            const bf16x4 va0 = *(const bf16x4*)&vrow[(4 * g) ^ xr];
            const bf16x4 va1 = *(const bf16x4*)&vrow[(16 + 4 * g) ^ xr];
            bf16x8 vf;
#pragma unroll
            for (int j = 0; j < 4; ++j) { vf[j] = va0[j]; vf[4 + j] = va1[j]; }
            acc[ct] = MFMA_16x16x32_BF16(pa0, vf, acc[ct]);
            if (liveB) {
                const bf16x4 vb0 = *(const bf16x4*)&vrow[(32 + 4 * g) ^ xr];
                const bf16x4 vb1 = *(const bf16x4*)&vrow[(48 + 4 * g) ^ xr];
                bf16x8 vf2;
#pragma unroll
                for (int j = 0; j < 4; ++j) { vf2[j] = vb0[j]; vf2[4 + j] = vb1[j]; }
                acc[ct] = MFMA_16x16x32_BF16(pa1, vf2, acc[ct]);
            }
        }
        __syncthreads();
    }

    float dn[4];
#pragma unroll
    for (int r = 0; r < 4; ++r) dn[r] = __shfl(l_s, 4 * g + r);
#pragma unroll
    for (int ct = 0; ct < 4; ++ct)
#pragma unroll
        for (int r = 0; r < 4; ++r)
            ctx[(rowoff + qbase + 4 * g + r) * Dm + h * 64 + ct * 16 + lr] =
                (__bf16)(acc[ct][r] / dn[r]);
}

// ---------------------------------------------------------------------------
extern "C" void kernel_launch(void* const* d_in, const int* in_sizes, int n_in,
                              void* d_out, int out_size, void* d_ws, size_t ws_size,
                              hipStream_t stream)
{
    (void)in_sizes; (void)n_in; (void)out_size; (void)ws_size;
    const float* z      = (const float*)d_in[0];
    const float* W_Q    = (const float*)d_in[1];
    const float* W_K    = (const float*)d_in[2];
    const float* W_V    = (const float*)d_in[3];
    const float* W_O    = (const float*)d_in[4];
    const float* W_fc   = (const float*)d_in[5];
    const float* W_proj = (const float*)d_in[6];
    const float* g1     = (const float*)d_in[7];
    const float* g2     = (const float*)d_in[8];
    float* out = (float*)d_out;

    char* ws = (char*)d_ws;
    const size_t MB = (size_t)1 << 20;
    __bf16* WtQKV  = (__bf16*)(ws + 0 * MB);   // [3072][1024]
    __bf16* WtO    = (__bf16*)(ws + 6 * MB);
    __bf16* Wtfc   = (__bf16*)(ws + 8 * MB);
    __bf16* Wtproj = (__bf16*)(ws + 16 * MB);
    __bf16* zn     = (__bf16*)(ws + 24 * MB);  // reused as ctx
    __bf16* Qb     = (__bf16*)(ws + 32 * MB);  // QKV out base; reused as h
    __bf16* Kbuf   = (__bf16*)(ws + 40 * MB);
    __bf16* Vtb    = (__bf16*)(ws + 48 * MB);
    __bf16* ffn1   = (__bf16*)(ws + 40 * MB);  // overlaps K,Vt (dead post-attn)
    __bf16* ctx    = zn;
    __bf16* hb     = Qb;

    const int Tt = 2048, Dm = 1024, Bb = 2, M = Bb * Tt, DFF = 4096;
    const dim3 blk256(256);

    // All weight transposes+converts in one launch
    transconv_all_kernel<<<12288, blk256, 0, stream>>>(
        W_Q, W_K, W_V, W_O, W_fc, W_proj, WtQKV, WtO, Wtfc, Wtproj);

    // zn = rmsnorm(z, g1)
    rmsnorm_kernel<<<M, blk256, 0, stream>>>(z, g1, zn);

    // Fused QKV: [4096][3072]; epilogue splits Q, K, and transposed Vt
    gemm_bf16<128, 128, 4><<<dim3(24, 32), blk256, 0, stream>>>(
        zn, WtQKV, Qb, nullptr, M, 3072, Dm);

    // attention -> ctx
    attn_kernel<<<1024, blk256, 0, stream>>>(Qb, Kbuf, Vtb, ctx);

    // z2 = z + ctx @ W_O  -> d_out (fp32)
    gemm_bf16<128, 64, 1><<<dim3(16, 32), blk256, 0, stream>>>(
        ctx, WtO, out, z, M, Dm, Dm);

    // h = rmsnorm(z2, g2)
    rmsnorm_kernel<<<M, blk256, 0, stream>>>(out, g2, hb);

    // ffn1 = gelu_erf(h @ W_fc)
    gemm_bf16<128, 128, 2><<<dim3(32, 32), blk256, 0, stream>>>(
        hb, Wtfc, ffn1, nullptr, M, DFF, Dm);

    // d_out += ffn1 @ W_proj
    gemm_bf16<128, 64, 3><<<dim3(16, 32), blk256, 0, stream>>>(
        ffn1, Wtproj, out, nullptr, M, Dm, DFF);
}

// Round 5
// 275.569 us; speedup vs baseline: 2.1617x; 1.0611x over previous
//
#include <hip/hip_runtime.h>
#include <hip/hip_bf16.h>
#include <math.h>

// ---------------------------------------------------------------------------
// GPT block on MI355X (gfx950). bf16 MFMA compute, fp32 accumulate.
// Workspace layout (MB = 1<<20), total 72 MB:
//   [ 0, 6)  WtQKV  bf16 [3072][1024]  (W_Q,W_K,W_V transposed, contiguous)
//   [ 6, 8)  WtO    bf16 [1024][1024]
//   [ 8,16)  Wtfc   bf16 [4096][1024]
//   [16,24)  Wtproj bf16 [1024][4096]
//   [24,32)  zn / ctx   bf16 [4096][1024]
//   [32,40)  Q / h      bf16 [4096][1024]
//   [40,48)  K          bf16 [4096][1024]
//   [48,56)  Vt         bf16 [32][64][2048]  (V transposed, kv-permuted)
//   [40,72)  ffn1       bf16 [4096][4096]  (overlaps K,Vt — dead after attn)
// d_out doubles as z2 (fp32): O-proj writes z2 = z + attn; proj does +=.
// GEMMs: 2-phase dbuf pipeline (T3-min), T2 XOR LDS swizzle, T1 XCD remap.
// Vt t-index is permuted within 32-blocks (16h+4g+j -> 8g+4h+j) so the PV
// B-fragment is a single 16B ds_read (conflict-free swizzle class).
// ---------------------------------------------------------------------------

typedef __bf16 bf16x8 __attribute__((ext_vector_type(8)));
typedef float  f32x4  __attribute__((ext_vector_type(4)));

#define MFMA_16x16x32_BF16(A, B, C) __builtin_amdgcn_mfma_f32_16x16x32_bf16((A), (B), (C), 0, 0, 0)

#define GLDS16(g, l) __builtin_amdgcn_global_load_lds( \
    (const __attribute__((address_space(1))) void*)(g), \
    (__attribute__((address_space(3))) void*)(l), 16, 0, 0)

// ---------------- fused transpose + fp32->bf16 convert for all 6 weights ----
__global__ __launch_bounds__(256) void transconv_all_kernel(
    const float* __restrict__ W_Q, const float* __restrict__ W_K,
    const float* __restrict__ W_V, const float* __restrict__ W_O,
    const float* __restrict__ W_fc, const float* __restrict__ W_proj,
    __bf16* __restrict__ WtQKV, __bf16* __restrict__ WtO,
    __bf16* __restrict__ Wtfc, __bf16* __restrict__ Wtproj)
{
    const int id = blockIdx.x;
    const float* src;
    __bf16* dst;
    int K, N, nx, t;
    if (id < 4096) {
        const int wsel = id >> 10;
        t = id & 1023;
        src = (wsel == 0) ? W_Q : (wsel == 1) ? W_K : (wsel == 2) ? W_V : W_O;
        dst = (wsel < 3) ? (WtQKV + (size_t)wsel * 1048576) : WtO;
        K = 1024; N = 1024; nx = 32;
    } else if (id < 8192) {
        t = id - 4096; src = W_fc; dst = Wtfc; K = 1024; N = 4096; nx = 128;
    } else {
        t = id - 8192; src = W_proj; dst = Wtproj; K = 4096; N = 1024; nx = 32;
    }
    const int n0 = (t % nx) * 32, k0 = (t / nx) * 32;

    __shared__ float tile[32][33];
    const int c = threadIdx.x & 31, r = threadIdx.x >> 5;
#pragma unroll
    for (int i = 0; i < 4; ++i)
        tile[r + 8 * i][c] = src[(size_t)(k0 + r + 8 * i) * N + n0 + c];
    __syncthreads();
#pragma unroll
    for (int i = 0; i < 4; ++i)
        dst[(size_t)(n0 + r + 8 * i) * K + k0 + c] = (__bf16)tile[c][r + 8 * i];
}

// ---------------- RMSNorm: fp32 [M][1024] -> bf16 [M][1024] -----------------
__global__ __launch_bounds__(256) void rmsnorm_kernel(
    const float* __restrict__ x, const float* __restrict__ gain,
    __bf16* __restrict__ out)
{
    const int row = blockIdx.x, t = threadIdx.x;
    const float4 v = ((const float4*)(x + (size_t)row * 1024))[t];
    float ss = v.x * v.x + v.y * v.y + v.z * v.z + v.w * v.w;
#pragma unroll
    for (int m = 1; m < 64; m <<= 1) ss += __shfl_xor(ss, m);
    __shared__ float red[4];
    const int wid = t >> 6, lane = t & 63;
    if (lane == 0) red[wid] = ss;
    __syncthreads();
    const float tot = red[0] + red[1] + red[2] + red[3];
    const float inv = rsqrtf(tot * (1.0f / 1024.0f) + 1e-5f);
    const float4 gv = ((const float4*)gain)[t];
    __bf16* o = out + (size_t)row * 1024 + t * 4;
    o[0] = (__bf16)(v.x * inv * gv.x);
    o[1] = (__bf16)(v.y * inv * gv.y);
    o[2] = (__bf16)(v.z * inv * gv.z);
    o[3] = (__bf16)(v.w * inv * gv.w);
}

// ---------------- GEMM: C[M][N] = A[M][K] * Bt[N][K]^T, bf16 MFMA ----------
// 2-phase dbuf: stage(t+1) issued before ds_read/MFMA of t; 1 barrier/K-step.
// EPI: 1 = out_f32 = res + acc; 2 = store bf16 gelu_erf(acc); 3 = out_f32 += acc
// EPI: 4 = fused QKV split: outp = Q base; K at +4M elems; Vt at +8M elems
template <int BM, int BN, int EPI>
__global__ __launch_bounds__(256) void gemm_bf16(
    const __bf16* __restrict__ A, const __bf16* __restrict__ Bt,
    void* __restrict__ outp, const float* __restrict__ res,
    int M, int N, int K)
{
    __shared__ __bf16 As[2][BM * 64];
    __shared__ __bf16 Bs[2][BN * 64];
    const int tid = threadIdx.x;

    // T1: bijective XCD-contiguous remap (all launches have nwg % 8 == 0)
    const int gx = gridDim.x, nwg = gx * gridDim.y;
    int bid = blockIdx.y * gx + blockIdx.x;
    if ((nwg & 7) == 0) bid = (bid & 7) * (nwg >> 3) + (bid >> 3);
    const int m0 = (bid / gx) * BM, n0 = (bid % gx) * BN;

    const int lane = tid & 63, w = tid >> 6;
    const int wm = w >> 1, wn = w & 1;
    const int lr = lane & 15, g = lane >> 4;
    const int srow = lane >> 3;                       // staging row-in-8
    const int scol = ((lane & 7) ^ srow) * 8;         // pre-swizzled source chunk
    const int xr8 = lr & 7;                           // read-side chunk XOR

    constexpr int MI = BM / 32, NI = BN / 32;
    f32x4 acc[MI][NI] = {};

    const __bf16* Abase = A + (size_t)m0 * K;
    const __bf16* Bbase = Bt + (size_t)n0 * K;

    auto STAGE = [&](int kb, int buf) {
#pragma unroll
        for (int j = 0; j < BM / 32; ++j) {
            const int s = j * 4 + w;
            GLDS16(Abase + (size_t)(s * 8 + srow) * K + kb + scol, &As[buf][s * 512]);
        }
#pragma unroll
        for (int j = 0; j < BN / 32; ++j) {
            const int s = j * 4 + w;
            GLDS16(Bbase + (size_t)(s * 8 + srow) * K + kb + scol, &Bs[buf][s * 512]);
        }
    };

    const int nt = K >> 6;
    STAGE(0, 0);
    __syncthreads();

    for (int t = 0; t < nt; ++t) {
        const int cur = t & 1;
        if (t + 1 < nt) STAGE((t + 1) << 6, cur ^ 1);

        bf16x8 af[2][MI], bfr[2][NI];
#pragma unroll
        for (int kk = 0; kk < 2; ++kk) {
#pragma unroll
            for (int i = 0; i < MI; ++i)
                af[kk][i] = *(const bf16x8*)
                    &As[cur][(wm * (BM / 2) + i * 16 + lr) * 64 + (((kk * 4 + g) ^ xr8) << 3)];
#pragma unroll
            for (int i = 0; i < NI; ++i)
                bfr[kk][i] = *(const bf16x8*)
                    &Bs[cur][(wn * (BN / 2) + i * 16 + lr) * 64 + (((kk * 4 + g) ^ xr8) << 3)];
        }
#pragma unroll
        for (int kk = 0; kk < 2; ++kk)
#pragma unroll
            for (int mi = 0; mi < MI; ++mi)
#pragma unroll
                for (int ni = 0; ni < NI; ++ni)
                    acc[mi][ni] = MFMA_16x16x32_BF16(af[kk][mi], bfr[kk][ni], acc[mi][ni]);
        if (t + 1 < nt) __syncthreads();
    }

#pragma unroll
    for (int mi = 0; mi < MI; ++mi)
#pragma unroll
        for (int ni = 0; ni < NI; ++ni) {
            const int colg = n0 + wn * (BN / 2) + ni * 16 + lr;
#pragma unroll
            for (int r = 0; r < 4; ++r) {
                const int rowg = m0 + wm * (BM / 2) + mi * 16 + 4 * g + r;
                const float v = acc[mi][ni][r];
                if constexpr (EPI == 1) {
                    const size_t idx = (size_t)rowg * N + colg;
                    ((float*)outp)[idx] = res[idx] + v;
                } else if constexpr (EPI == 2) {
                    const size_t idx = (size_t)rowg * N + colg;
                    ((__bf16*)outp)[idx] =
                        (__bf16)(0.5f * v * (1.0f + erff(v * 0.70710678118654752f)));
                } else if constexpr (EPI == 3) {
                    const size_t idx = (size_t)rowg * N + colg;
                    ((float*)outp)[idx] += v;
                } else {  // EPI == 4: QKV split
                    __bf16* base = (__bf16*)outp;
                    const int seg = colg >> 10;       // 0=Q, 1=K, 2=V
                    const int cg = colg & 1023;
                    if (seg < 2) {
                        base[(size_t)seg * 4194304 + (size_t)rowg * 1024 + cg] = (__bf16)v;
                    } else {
                        // Vt[b][h][d][t'] with within-32 t-permutation:
                        // t = 16h+4g+j (mod 32) stored at 8g+4h+j
                        const int tt = rowg & 2047;
                        const int r32 = tt & 31;
                        const int p = ((r32 & 12) << 1) | ((r32 >> 2) & 4) | (r32 & 3);
                        base[8388608 +
                             ((size_t)((rowg >> 11) * 16 + (cg >> 6)) * 64 + (cg & 63)) * 2048 +
                             ((tt & ~31) | p)] = (__bf16)v;
                    }
                }
            }
        }
}

// ---------------- Flash-style causal attention (LDS-staged, dbuf) -----------
// Grid: blockIdx.x = qc*32 + bh. 4 waves, 16 q-rows each. KV steps of 64.
__global__ __launch_bounds__(256) void attn_kernel(
    const __bf16* __restrict__ Q, const __bf16* __restrict__ Kb,
    const __bf16* __restrict__ Vt, __bf16* __restrict__ ctx)
{
    const int Dm = 1024, T = 2048;
    const int tid = threadIdx.x;
    const int w = tid >> 6, lane = tid & 63;
    const int lr = lane & 15, g = lane >> 4;
    const int bx = blockIdx.x;
    const int qc = bx >> 5, bh = bx & 31, b = bh >> 4, h = bh & 15;
    const int qbase = qc * 64 + w * 16;
    const size_t rowoff = (size_t)b * T;
    const __bf16* Qp = Q + rowoff * Dm + h * 64;
    const __bf16* Kp = Kb + rowoff * Dm + h * 64;        // row t, stride 1024
    const __bf16* Vtp = Vt + (size_t)bh * 64 * 2048;     // row d, stride 2048

    __shared__ __bf16 Ks[2][64 * 64];
    __shared__ __bf16 Vs[2][64 * 64];

    // Q fragments pre-scaled by 1/8 (exact in bf16: power of 2)
    bf16x8 qf0 = *(const bf16x8*)&Qp[(size_t)(qbase + lr) * Dm + g * 8];
    bf16x8 qf1 = *(const bf16x8*)&Qp[(size_t)(qbase + lr) * Dm + 32 + g * 8];
#pragma unroll
    for (int j = 0; j < 8; ++j) {
        qf0[j] = (__bf16)((float)qf0[j] * 0.125f);
        qf1[j] = (__bf16)((float)qf1[j] * 0.125f);
    }

    const int srow = lane >> 3;
    const int schunk = (lane & 7) ^ srow;

    f32x4 acc[4] = {};
    float m_s = -__builtin_inff(), l_s = 0.0f;
    const int nsteps = qc + 1;
    const f32x4 zacc = {0.0f, 0.0f, 0.0f, 0.0f};
    const int xr = (lr & 7) << 3;
    const int qg = qbase + lr;

#pragma unroll
    for (int j = 0; j < 2; ++j) {
        const int row = j * 32 + w * 8 + srow;
        GLDS16(Kp + (size_t)row * Dm + schunk * 8, &Ks[0][(j * 32 + w * 8) * 64]);
        GLDS16(Vtp + (size_t)row * T + schunk * 8, &Vs[0][(j * 32 + w * 8) * 64]);
    }
    __syncthreads();

    for (int t = 0; t < nsteps; ++t) {
        const int kvb = t * 64, cur = t & 1;
        if (t + 1 < nsteps) {
#pragma unroll
            for (int j = 0; j < 2; ++j) {
                const int row = j * 32 + w * 8 + srow;
                GLDS16(Kp + (size_t)(kvb + 64 + row) * Dm + schunk * 8,
                       &Ks[cur ^ 1][(j * 32 + w * 8) * 64]);
                GLDS16(Vtp + (size_t)row * T + kvb + 64 + schunk * 8,
                       &Vs[cur ^ 1][(j * 32 + w * 8) * 64]);
            }
        }

        // ---- QK^T: four 16-kv sub-tiles (Q pre-scaled) ----
        float sv[4][4];
#pragma unroll
        for (int s4 = 0; s4 < 4; ++s4) {
            const int kv0 = kvb + s4 * 16;
            if (kv0 <= qbase + 15) {
                const int row = s4 * 16 + lr;
                const bf16x8 kfa = *(const bf16x8*)&Ks[cur][row * 64 + ((g * 8) ^ xr)];
                const bf16x8 kfb = *(const bf16x8*)&Ks[cur][row * 64 + ((32 + g * 8) ^ xr)];
                f32x4 st = MFMA_16x16x32_BF16(kfa, qf0, zacc);
                st = MFMA_16x16x32_BF16(kfb, qf1, st);
                const bool domask = (kv0 + 15 > qbase);
#pragma unroll
                for (int r = 0; r < 4; ++r) {
                    float x = st[r];
                    if (domask && (kv0 + 4 * g + r > qg)) x = -__builtin_inff();
                    sv[s4][r] = x;
                }
            } else {
#pragma unroll
                for (int r = 0; r < 4; ++r) sv[s4][r] = -__builtin_inff();
            }
        }

        // ---- online softmax with defer-rescale (T13, THR=8) ----
        float tm = sv[0][0];
#pragma unroll
        for (int s4 = 0; s4 < 4; ++s4)
#pragma unroll
            for (int r = 0; r < 4; ++r) tm = fmaxf(tm, sv[s4][r]);
        tm = fmaxf(tm, __shfl_xor(tm, 16));
        tm = fmaxf(tm, __shfl_xor(tm, 32));

        float m_use = m_s;
        if (!__all(tm - m_s <= 8.0f)) {
            m_use = fmaxf(m_s, tm);
            const float corr = __expf(m_s - m_use);
            l_s *= corr;
            float cr[4];
#pragma unroll
            for (int r = 0; r < 4; ++r) cr[r] = __shfl(corr, 4 * g + r);
#pragma unroll
            for (int ct = 0; ct < 4; ++ct) {
                acc[ct][0] *= cr[0]; acc[ct][1] *= cr[1];
                acc[ct][2] *= cr[2]; acc[ct][3] *= cr[3];
            }
            m_s = m_use;
        }

        float rs = 0.0f;
#pragma unroll
        for (int s4 = 0; s4 < 4; ++s4)
#pragma unroll
            for (int r = 0; r < 4; ++r) {
                sv[s4][r] = __expf(sv[s4][r] - m_use);
                rs += sv[s4][r];
            }
        rs += __shfl_xor(rs, 16);
        rs += __shfl_xor(rs, 32);
        l_s += rs;

        // ---- PV: single 16B V fragments (kv-permuted Vt layout) ----
        bf16x8 pa0, pa1;
#pragma unroll
        for (int r = 0; r < 4; ++r) {
            pa0[r] = (__bf16)sv[0][r];
            pa0[4 + r] = (__bf16)sv[1][r];
            pa1[r] = (__bf16)sv[2][r];
            pa1[4 + r] = (__bf16)sv[3][r];
        }
        const bool liveB = (kvb + 32 <= qbase + 15);
#pragma unroll
        for (int ct = 0; ct < 4; ++ct) {
            const __bf16* vrow = &Vs[cur][(ct * 16 + lr) * 64];
            const bf16x8 vf = *(const bf16x8*)&vrow[(8 * g) ^ xr];
            acc[ct] = MFMA_16x16x32_BF16(pa0, vf, acc[ct]);
            if (liveB) {
                const bf16x8 vf2 = *(const bf16x8*)&vrow[(32 + 8 * g) ^ xr];
                acc[ct] = MFMA_16x16x32_BF16(pa1, vf2, acc[ct]);
            }
        }
        __syncthreads();
    }

    float dn[4];
#pragma unroll
    for (int r = 0; r < 4; ++r) dn[r] = __shfl(l_s, 4 * g + r);
#pragma unroll
    for (int ct = 0; ct < 4; ++ct)
#pragma unroll
        for (int r = 0; r < 4; ++r)
            ctx[(rowoff + qbase + 4 * g + r) * Dm + h * 64 + ct * 16 + lr] =
                (__bf16)(acc[ct][r] / dn[r]);
}

// ---------------------------------------------------------------------------
extern "C" void kernel_launch(void* const* d_in, const int* in_sizes, int n_in,
                              void* d_out, int out_size, void* d_ws, size_t ws_size,
                              hipStream_t stream)
{
    (void)in_sizes; (void)n_in; (void)out_size; (void)ws_size;
    const float* z      = (const float*)d_in[0];
    const float* W_Q    = (const float*)d_in[1];
    const float* W_K    = (const float*)d_in[2];
    const float* W_V    = (const float*)d_in[3];
    const float* W_O    = (const float*)d_in[4];
    const float* W_fc   = (const float*)d_in[5];
    const float* W_proj = (const float*)d_in[6];
    const float* g1     = (const float*)d_in[7];
    const float* g2     = (const float*)d_in[8];
    float* out = (float*)d_out;

    char* ws = (char*)d_ws;
    const size_t MB = (size_t)1 << 20;
    __bf16* WtQKV  = (__bf16*)(ws + 0 * MB);   // [3072][1024]
    __bf16* WtO    = (__bf16*)(ws + 6 * MB);
    __bf16* Wtfc   = (__bf16*)(ws + 8 * MB);
    __bf16* Wtproj = (__bf16*)(ws + 16 * MB);
    __bf16* zn     = (__bf16*)(ws + 24 * MB);  // reused as ctx
    __bf16* Qb     = (__bf16*)(ws + 32 * MB);  // QKV out base; reused as h
    __bf16* Kbuf   = (__bf16*)(ws + 40 * MB);
    __bf16* Vtb    = (__bf16*)(ws + 48 * MB);
    __bf16* ffn1   = (__bf16*)(ws + 40 * MB);  // overlaps K,Vt (dead post-attn)
    __bf16* ctx    = zn;
    __bf16* hb     = Qb;

    const int Tt = 2048, Dm = 1024, Bb = 2, M = Bb * Tt, DFF = 4096;
    const dim3 blk256(256);

    // All weight transposes+converts in one launch
    transconv_all_kernel<<<12288, blk256, 0, stream>>>(
        W_Q, W_K, W_V, W_O, W_fc, W_proj, WtQKV, WtO, Wtfc, Wtproj);

    // zn = rmsnorm(z, g1)
    rmsnorm_kernel<<<M, blk256, 0, stream>>>(z, g1, zn);

    // Fused QKV: [4096][3072]; epilogue splits Q, K, and permuted-transposed Vt
    gemm_bf16<128, 128, 4><<<dim3(24, 32), blk256, 0, stream>>>(
        zn, WtQKV, Qb, nullptr, M, 3072, Dm);

    // attention -> ctx
    attn_kernel<<<1024, blk256, 0, stream>>>(Qb, Kbuf, Vtb, ctx);

    // z2 = z + ctx @ W_O  -> d_out (fp32)
    gemm_bf16<128, 64, 1><<<dim3(16, 32), blk256, 0, stream>>>(
        ctx, WtO, out, z, M, Dm, Dm);

    // h = rmsnorm(z2, g2)
    rmsnorm_kernel<<<M, blk256, 0, stream>>>(out, g2, hb);

    // ffn1 = gelu_erf(h @ W_fc)
    gemm_bf16<128, 128, 2><<<dim3(32, 32), blk256, 0, stream>>>(
        hb, Wtfc, ffn1, nullptr, M, DFF, Dm);

    // d_out += ffn1 @ W_proj
    gemm_bf16<128, 64, 3><<<dim3(16, 32), blk256, 0, stream>>>(
        ffn1, Wtproj, out, nullptr, M, Dm, DFF);
}